// Round 5
// baseline (148.514 us; speedup 1.0000x reference)
//
#include <hip/hip_runtime.h>

typedef float f32x4  __attribute__((ext_vector_type(4)));
typedef float f32x16 __attribute__((ext_vector_type(16)));
typedef short s16x8  __attribute__((ext_vector_type(8)));
typedef unsigned short u16;

#define LL 2048
#define DD 64
#define NITER 32
#define SC_OFF 4194304ull

struct SMem {
    u16 Khi[2][64][72];   // double-buffered key tile (key row, d), bf16
    u16 VT [2][64][72];   // double-buffered V^T tile (d row, key col), bf16
    u16 P  [8][1024];     // per-wave private 32q x 32k bf16, XOR-swizzled
};

__device__ __forceinline__ u16 bf16_rne(float x) {
    unsigned u = __builtin_bit_cast(unsigned, x);
    return (u16)((u + 0x7FFFu + ((u >> 16) & 1u)) >> 16);
}
__device__ __forceinline__ float bf16f(u16 h) {
    unsigned u = (unsigned)h << 16;
    return __builtin_bit_cast(float, u);
}

__global__ __launch_bounds__(512, 4)
void psam_kernel(const float* __restrict__ Qg0, const float* __restrict__ Kg0,
                 const float* __restrict__ Vg0, const int* __restrict__ Mg0,
                 float* __restrict__ out)
{
    __shared__ SMem sm;
    const int tid = threadIdx.x;
    const int w = tid >> 6, l = tid & 63;
    const int j31 = l & 31, h = l >> 5;   // lane index within 32, half-wave
    const int cw = w & 1, iw = w >> 1;    // key-half, query chunk of 32
    const int cwj = cw * 32 + j31;        // this lane's key within the 64-key tile

    // XCD-aware swizzle: all 16 blocks of a (b,h) land on one XCD's L2
    const int bid = ((int)blockIdx.x & 7) * 64 + ((int)blockIdx.x >> 3);
    const int bh = bid >> 4;
    const int m0 = (bid & 15) << 7;       // q-row tile start
    const int bB = bh >> 4;               // batch index (H=16)

    const float* Kg = Kg0 + (size_t)bh * LL * DD;
    const float* Vg = Vg0 + (size_t)bh * LL * DD;
    const int*   Mg = Mg0 + (size_t)bB * LL;
    float* So = out + SC_OFF + (size_t)bh * LL * LL + (size_t)m0 * LL;
    float* Oo = out + ((size_t)bh * LL + m0) * DD;

    // ---------- Q hi/lo fragments: direct per-lane global load ----------
    s16x8 qfh[4], qfl[4];
    {
        const float* qr = Qg0 + ((size_t)bh * LL + m0 + iw * 32 + j31) * DD + h * 8;
#pragma unroll
        for (int ks = 0; ks < 4; ++ks) {
            f32x4 a = *(const f32x4*)(qr + ks * 16);
            f32x4 b = *(const f32x4*)(qr + ks * 16 + 4);
#pragma unroll
            for (int i = 0; i < 4; ++i) {
                u16 hi = bf16_rne(a[i]);
                qfh[ks][i] = (short)hi;
                qfl[ks][i] = (short)bf16_rne(a[i] - bf16f(hi));
                hi = bf16_rne(b[i]);
                qfh[ks][4 + i] = (short)hi;
                qfl[ks][4 + i] = (short)bf16_rne(b[i] - bf16f(hi));
            }
        }
    }

    // ---------- tile-0 staging + tile-1 register prefetch ----------
    const int kc = tid >> 3, kd = (tid & 7) * 8;     // K staging: row, col base
    const int vc = tid & 63, vd = (tid >> 6) * 8;    // V staging: row, col base
    f32x4 kvx, kvy, vvx, vvy;
    {
        const f32x4* s = (const f32x4*)(Kg + (size_t)kc * DD + kd);
        kvx = s[0]; kvy = s[1];
        const f32x4* s2 = (const f32x4*)(Vg + (size_t)vc * DD + vd);
        vvx = s2[0]; vvy = s2[1];
    }
    {
        s16x8 kv;
#pragma unroll
        for (int i = 0; i < 4; ++i) { kv[i] = (short)bf16_rne(kvx[i]); kv[4 + i] = (short)bf16_rne(kvy[i]); }
        *(s16x8*)&sm.Khi[0][kc][kd] = kv;
#pragma unroll
        for (int i = 0; i < 4; ++i) {
            sm.VT[0][vd + i][vc]     = bf16_rne(vvx[i]);
            sm.VT[0][vd + 4 + i][vc] = bf16_rne(vvy[i]);
        }
    }
    {
        const f32x4* s = (const f32x4*)(Kg + (size_t)(64 + kc) * DD + kd);
        kvx = s[0]; kvy = s[1];
        const f32x4* s2 = (const f32x4*)(Vg + (size_t)(64 + vc) * DD + vd);
        vvx = s2[0]; vvy = s2[1];
    }
    float blc = -1.0e9f * (float)Mg[cwj];
    float bln = -1.0e9f * (float)Mg[64 + cwj];

    f32x16 accO0, accO1;   // OUT^T partials: d 0..63 x own 32 queries, own 32 keys
#pragma unroll
    for (int e = 0; e < 16; ++e) { accO0[e] = 0.0f; accO1[e] = 0.0f; }

    char* spw = (char*)&sm.P[w][0];
    asm volatile("s_waitcnt lgkmcnt(0)" ::: "memory");
    __builtin_amdgcn_s_barrier();   // tile-0 staging visible

    int buf = 0;
    for (int t = 0; t < NITER; ++t) {
        const int j0 = t * 64;

        // ---- S = Q * K^T  (A=Q frags, B=K frags -> col=lane=key) ----
        f32x16 accS;
#pragma unroll
        for (int e = 0; e < 16; ++e) accS[e] = 0.0f;
#pragma unroll
        for (int ks = 0; ks < 4; ++ks) {
            s16x8 kf = *(const s16x8*)&sm.Khi[buf][cwj][ks * 16 + h * 8];
            accS = __builtin_amdgcn_mfma_f32_32x32x16_bf16(qfh[ks], kf, accS, 0, 0, 0);
            accS = __builtin_amdgcn_mfma_f32_32x32x16_bf16(qfl[ks], kf, accS, 0, 0, 0);
        }
        // C/D layout: col(key)=lane&31, row(query q)=r + 8g + 4h
        const float bl = blc;
        float* sp = So + (size_t)(iw * 32 + 4 * h) * LL + j0 + cwj;
#pragma unroll
        for (int g = 0; g < 4; ++g) {
#pragma unroll
            for (int r = 0; r < 4; ++r) {
                float x  = accS[g * 4 + r] * 0.125f + bl;              // qk/8 + mask*(-1e9)
                float tt = __builtin_amdgcn_exp2f(x * 1.44269504f);    // e^x
                float p  = __builtin_amdgcn_logf(1.0f + tt) * 3.38450771757785852e-4f; // ln(1+e^x)/2048
                __builtin_nontemporal_store(p, sp + (size_t)(8 * g + r) * LL);
                const int q = 8 * g + 4 * h + r;                       // local query row
                *(u16*)(spw + q * 64 + ((j31 * 2) ^ ((q & 3) << 4))) = bf16_rne(p);
            }
        }

        // ---- OUT^T += V^T(own keys) * P^T  — wave-private, no barrier ----
#pragma unroll
        for (int ks2 = 0; ks2 < 2; ++ks2) {
            s16x8 pb = *(const s16x8*)(spw + j31 * 64 + ((ks2 * 32 + h * 16) ^ ((j31 & 3) << 4)));
            s16x8 va0 = *(const s16x8*)&sm.VT[buf][j31][cw * 32 + ks2 * 16 + h * 8];
            accO0 = __builtin_amdgcn_mfma_f32_32x32x16_bf16(va0, pb, accO0, 0, 0, 0);
            s16x8 va1 = *(const s16x8*)&sm.VT[buf][32 + j31][cw * 32 + ks2 * 16 + h * 8];
            accO1 = __builtin_amdgcn_mfma_f32_32x32x16_bf16(va1, pb, accO1, 0, 0, 0);
        }

        // ---- write tile t+1 staging regs into the other buffer ----
        if (t + 1 < NITER) {
            s16x8 kv;
#pragma unroll
            for (int i = 0; i < 4; ++i) { kv[i] = (short)bf16_rne(kvx[i]); kv[4 + i] = (short)bf16_rne(kvy[i]); }
            *(s16x8*)&sm.Khi[buf ^ 1][kc][kd] = kv;
#pragma unroll
            for (int i = 0; i < 4; ++i) {
                sm.VT[buf ^ 1][vd + i][vc]     = bf16_rne(vvx[i]);
                sm.VT[buf ^ 1][vd + 4 + i][vc] = bf16_rne(vvy[i]);
            }
        }
        // ---- prefetch tile t+2 into registers ----
        {
            const int tp = (t + 2 < NITER) ? (t + 2) : (NITER - 1);
            const f32x4* s1 = (const f32x4*)(Kg + (size_t)(tp * 64 + kc) * DD + kd);
            kvx = s1[0]; kvy = s1[1];
            const f32x4* s2 = (const f32x4*)(Vg + (size_t)(tp * 64 + vc) * DD + vd);
            vvx = s2[0]; vvy = s2[1];
            blc = bln;
            bln = -1.0e9f * (float)Mg[tp * 64 + cwj];
        }
        asm volatile("s_waitcnt lgkmcnt(0)" ::: "memory");  // staging writes drained; stores stay in flight
        __builtin_amdgcn_s_barrier();
        buf ^= 1;
    }

    // ---- epilogue: cross-wave (key-half) reduction via LDS, then store OUT ----
    float* red = (float*)&sm;   // 32 KB scratch aliasing Khi+VT (all waves past final barrier)
    if (cw == 1) {
#pragma unroll
        for (int db = 0; db < 2; ++db) {
            const f32x16& a = db ? accO1 : accO0;
#pragma unroll
            for (int g = 0; g < 4; ++g)
#pragma unroll
                for (int r = 0; r < 4; ++r) {
                    const int row = db * 32 + 8 * g + 4 * h + r;   // d within 0..63
                    red[(size_t)(iw * 64 + row) * 32 + j31] = a[g * 4 + r];
                }
        }
    }
    __syncthreads();
    if (cw == 0) {
        float* op = Oo + (size_t)(iw * 32 + j31) * DD;
#pragma unroll
        for (int db = 0; db < 2; ++db) {
            const f32x16& a = db ? accO1 : accO0;
#pragma unroll
            for (int g = 0; g < 4; ++g) {
                f32x4 o;
#pragma unroll
                for (int r = 0; r < 4; ++r) {
                    const int row = db * 32 + 8 * g + 4 * h + r;
                    o[r] = a[g * 4 + r] + red[(size_t)(iw * 64 + row) * 32 + j31];
                }
                *(f32x4*)(op + db * 32 + 8 * g + 4 * h) = o;
            }
        }
    }
}

extern "C" void kernel_launch(void* const* d_in, const int* in_sizes, int n_in,
                              void* d_out, int out_size, void* d_ws, size_t ws_size,
                              hipStream_t stream) {
    const float* q    = (const float*)d_in[0];
    const float* k    = (const float*)d_in[1];
    const float* v    = (const float*)d_in[2];
    const int*   mask = (const int*)d_in[5];   // p_q, p_k unused by reference
    float* out = (float*)d_out;
    hipLaunchKernelGGL(psam_kernel, dim3(512), dim3(512), 0, stream, q, k, v, mask, out);
}